// Round 10
// baseline (215.956 us; speedup 1.0000x reference)
//
#include <hip/hip_runtime.h>
#include <math.h>

#define EMBED 1024
#define NH    16
#define DH    64
#define BATCH 2
#define SEQ   2048
#define MTOT  4096
#define BHTOT 32

typedef float f32x4  __attribute__((ext_vector_type(4)));
typedef float f32x16 __attribute__((ext_vector_type(16)));
typedef short s16x8  __attribute__((ext_vector_type(8)));
typedef short s16x4  __attribute__((ext_vector_type(4)));
typedef unsigned u32x2 __attribute__((ext_vector_type(2)));
typedef unsigned u32x4 __attribute__((ext_vector_type(4)));

#define AS1 __attribute__((address_space(1)))
#define AS3 __attribute__((address_space(3)))

__device__ __forceinline__ unsigned short bf16_rne(float f) {
    unsigned u = __builtin_bit_cast(unsigned, f);
    return (unsigned short)((u + 0x7FFFu + ((u >> 16) & 1u)) >> 16);
}
__device__ __forceinline__ float bf16_f(unsigned short h) {
    unsigned u = ((unsigned)h) << 16;
    return __builtin_bit_cast(float, u);
}
__device__ __forceinline__ void split2(float v, unsigned short& hi, unsigned short& lo) {
    hi = bf16_rne(v);
    lo = bf16_rne(v - bf16_f(hi));
}
__device__ __forceinline__ void gload16(const void* g, void* l) {
    __builtin_amdgcn_global_load_lds((const AS1 void*)g, (AS3 void*)l, 16, 0, 0);
}
__device__ __forceinline__ unsigned cvt_pk_bf16(float lo, float hi) {
    unsigned r;
    asm volatile("v_cvt_pk_bf16_f32 %0, %1, %2" : "=v"(r) : "v"(lo), "v"(hi));
    return r;
}
#define MFMA16(a, b, c) __builtin_amdgcn_mfma_f32_16x16x32_bf16((a), (b), (c), 0, 0, 0)
#define MFMA32(a, b, c) __builtin_amdgcn_mfma_f32_32x32x16_bf16((a), (b), (c), 0, 0, 0)

// ---------------------------------------------------------------------------
// splitX: X fp32 [M][K] -> Xh, Xl bf16 (same layout, hi/lo split)
// ---------------------------------------------------------------------------
__global__ __launch_bounds__(256)
void splitX_kernel(const float* __restrict__ X, unsigned short* __restrict__ Xh,
                   unsigned short* __restrict__ Xl)
{
    const size_t i = ((size_t)blockIdx.x * 256 + threadIdx.x) * 8;
    float4 a = *(const float4*)&X[i];
    float4 b = *(const float4*)&X[i + 4];
    float v[8] = {a.x, a.y, a.z, a.w, b.x, b.y, b.z, b.w};
    s16x8 h8, l8;
#pragma unroll
    for (int e = 0; e < 8; ++e) {
        unsigned short h, l; split2(v[e], h, l);
        h8[e] = (short)h; l8[e] = (short)l;
    }
    *(s16x8*)&Xh[i] = h8;
    *(s16x8*)&Xl[i] = l8;
}

// ---------------------------------------------------------------------------
// splitT: W fp32 [Kd][Nd]  ->  HiT, LoT bf16 [Nd][Kd] (transposed + hi/lo split)
// ---------------------------------------------------------------------------
__global__ __launch_bounds__(256)
void splitT_kernel(const float* __restrict__ W, unsigned short* __restrict__ HiT,
                   unsigned short* __restrict__ LoT, int Kd, int Nd)
{
    __shared__ float T[32][33];
    const int tid = threadIdx.x;
    const int n0 = blockIdx.x * 32, k0 = blockIdx.y * 32;
    {
        const int row = tid >> 3, c4 = (tid & 7) * 4;
        float4 v = *(const float4*)&W[(size_t)(k0 + row) * Nd + n0 + c4];
        T[row][c4] = v.x; T[row][c4 + 1] = v.y; T[row][c4 + 2] = v.z; T[row][c4 + 3] = v.w;
    }
    __syncthreads();
    {
        const int nr = tid >> 3, c4 = (tid & 7) * 4;
        s16x4 h4, l4;
#pragma unroll
        for (int e = 0; e < 4; ++e) {
            unsigned short h, l;
            split2(T[c4 + e][nr], h, l);
            h4[e] = (short)h; l4[e] = (short)l;
        }
        *(s16x4*)&HiT[(size_t)(n0 + nr) * Kd + k0 + c4] = h4;
        *(s16x4*)&LoT[(size_t)(n0 + nr) * Kd + k0 + c4] = l4;
    }
}

// ---------------------------------------------------------------------------
// QKV GEMM (all-bf16), 128x64 tile, BK=32, DOUBLE-BUFFERED (48 KB LDS ->
// still 3 blocks/CU) with issue-early staging. Grid 1536 = 8 XCD x 192
// (m-fastest). Per wave: 64x32 output, 8 accumulators, combo-outer MFMA.
// ---------------------------------------------------------------------------
__global__ __launch_bounds__(256)
void qkv_gemm_kernel(const unsigned short* __restrict__ Xh_g, const unsigned short* __restrict__ Xl_g,
                     const unsigned short* __restrict__ BhT, const unsigned short* __restrict__ BlT,
                     const float* __restrict__ bias,
                     unsigned short* __restrict__ Qh, unsigned short* __restrict__ Ql,
                     unsigned short* __restrict__ Kh, unsigned short* __restrict__ Kl,
                     unsigned short* __restrict__ Vh, unsigned short* __restrict__ Vl)
{
    constexpr int KD = 1024;
    // per buf (shorts): Ah [0,4096) Al [4096,8192) Bh [8192,10240) Bl [10240,12288)
    __shared__ __align__(16) short SB[2][12288];   // 48 KB total

    const int tid = threadIdx.x, lane = tid & 63, wid = tid >> 6;
    const int g = lane >> 4, ln = lane & 15;
    const int wm = wid >> 1, wn = wid & 1;

    // XCD swizzle: xcd = bid&7 owns 192 tiles = 4 m-rows x 48 n (m-fastest)
    const int bid = blockIdx.x;
    const int u = bid >> 3, xcd = bid & 7;
    const int by = xcd * 4 + (u & 3);   // m-tile 0..31
    const int bx = u >> 2;              // n-tile 0..47
    const int m0 = by * 128, n0 = bx * 64;

    f32x4 acc[4][2];
#pragma unroll
    for (int i = 0; i < 4; ++i)
#pragma unroll
        for (int j = 0; j < 2; ++j) acc[i][j] = (f32x4){0.f, 0.f, 0.f, 0.f};

    const int srow = lane >> 2, ss = lane & 3;
    const unsigned short* gb = (wid == 0) ? Xh_g : (wid == 1) ? Xl_g
                             : (wid == 2) ? BhT  : BlT;
    const int roff = (wid < 2) ? m0 : n0;
    const int lbase = (wid == 0) ? 0 : (wid == 1) ? 4096 : (wid == 2) ? 8192 : 10240;

    // prologue: stage k-tile 0 into buf 0
    if (wid < 2) {
        short* lb = &SB[0][lbase];
#pragma unroll
        for (int j = 0; j < 8; ++j) {
            int row_loc = j * 16 + srow;
            int kc = ss ^ ((row_loc >> 1) & 3);
            gload16(gb + (size_t)(roff + row_loc) * KD + kc * 8, lb + j * 512);
        }
    } else {
        short* lb = &SB[0][lbase];
#pragma unroll
        for (int j = 0; j < 4; ++j) {
            int row_loc = j * 16 + srow;
            int kc = ss ^ ((row_loc >> 1) & 3);
            gload16(gb + (size_t)(roff + row_loc) * KD + kc * 8, lb + j * 512);
        }
    }

    for (int it = 0; it < 32; ++it) {
        const int cur = it & 1;
        __syncthreads();   // stage(it) landed; reads of buf[cur] (iter it-2) done
        if (it + 1 < 32) {
            const int k0n = (it + 1) * 32;
            short* lb = &SB[cur ^ 1][lbase];
            if (wid < 2) {
#pragma unroll
                for (int j = 0; j < 8; ++j) {
                    int row_loc = j * 16 + srow;
                    int kc = ss ^ ((row_loc >> 1) & 3);
                    gload16(gb + (size_t)(roff + row_loc) * KD + k0n + kc * 8, lb + j * 512);
                }
            } else {
#pragma unroll
                for (int j = 0; j < 4; ++j) {
                    int row_loc = j * 16 + srow;
                    int kc = ss ^ ((row_loc >> 1) & 3);
                    gload16(gb + (size_t)(roff + row_loc) * KD + k0n + kc * 8, lb + j * 512);
                }
            }
        }
        const short* Ah = &SB[cur][0];
        const short* Al = &SB[cur][4096];
        const short* Bh = &SB[cur][8192];
        const short* Bl = &SB[cur][10240];

        s16x8 fah[4], fal[4], fbh[2], fbl[2];
#pragma unroll
        for (int am = 0; am < 4; ++am) {
            int m_loc = wm * 64 + am * 16 + ln;
            int sl = (g ^ ((m_loc >> 1) & 3)) * 8;
            fah[am] = *(const s16x8*)&Ah[m_loc * 32 + sl];
            fal[am] = *(const s16x8*)&Al[m_loc * 32 + sl];
        }
#pragma unroll
        for (int bn = 0; bn < 2; ++bn) {
            int n_loc = wn * 32 + bn * 16 + ln;
            int sl = (g ^ ((n_loc >> 1) & 3)) * 8;
            fbh[bn] = *(const s16x8*)&Bh[n_loc * 32 + sl];
            fbl[bn] = *(const s16x8*)&Bl[n_loc * 32 + sl];
        }
        // combo-outer: reuse distance 8 on each accumulator
#pragma unroll
        for (int am = 0; am < 4; ++am)
#pragma unroll
            for (int bn = 0; bn < 2; ++bn)
                acc[am][bn] = MFMA16(fah[am], fbh[bn], acc[am][bn]);
#pragma unroll
        for (int am = 0; am < 4; ++am)
#pragma unroll
            for (int bn = 0; bn < 2; ++bn)
                acc[am][bn] = MFMA16(fah[am], fbl[bn], acc[am][bn]);
#pragma unroll
        for (int am = 0; am < 4; ++am)
#pragma unroll
            for (int bn = 0; bn < 2; ++bn)
                acc[am][bn] = MFMA16(fal[am], fbh[bn], acc[am][bn]);
    }

    // epilogue: bias + split scatter (C/D: row=(lane>>4)*4+r, col=lane&15)
#pragma unroll
    for (int am = 0; am < 4; ++am)
#pragma unroll
        for (int bn = 0; bn < 2; ++bn) {
            int n = n0 + wn * 32 + bn * 16 + ln;
            float bv = bias[n];
            int sec = n >> 10, cc = n & 1023, h = cc >> 6, d = cc & 63;
#pragma unroll
            for (int r = 0; r < 4; ++r) {
                int m = m0 + wm * 64 + am * 16 + g * 4 + r;
                int bb = m >> 11, t = m & 2047;
                int bh_i = bb * NH + h;
                float val = acc[am][bn][r] + bv;
                unsigned short hi, lo;
                if (sec == 0) {
                    val *= 0.125f; split2(val, hi, lo);
                    size_t idx = ((size_t)bh_i * SEQ + t) * DH + d;
                    Qh[idx] = hi; Ql[idx] = lo;
                } else if (sec == 1) {
                    split2(val, hi, lo);
                    size_t idx = ((size_t)bh_i * SEQ + t) * DH + d;
                    Kh[idx] = hi; Kl[idx] = lo;
                } else {
                    split2(val, hi, lo);
                    size_t idx = ((size_t)bh_i * DH + d) * SEQ + t;   // V transposed
                    Vh[idx] = hi; Vl[idx] = lo;
                }
            }
        }
}

// ---------------------------------------------------------------------------
// Attention, 32x32 swapped-operand structure + 2-phase pipelined K/V staging
// (double-buffered, 64 KB LDS). Masked waves still issue their stage.
// Defer-max THR=8; interleaved MFMA accumulators.  (unchanged from r9)
// ---------------------------------------------------------------------------
__global__ __launch_bounds__(256)
void attn_kernel(const unsigned short* __restrict__ Qh_g, const unsigned short* __restrict__ Ql_g,
                 const unsigned short* __restrict__ Kh_g, const unsigned short* __restrict__ Kl_g,
                 const unsigned short* __restrict__ Vh_g, const unsigned short* __restrict__ Vl_g,
                 unsigned short* __restrict__ Yh, unsigned short* __restrict__ Yl)
{
    __shared__ __align__(16) short SM[2][16384];   // 64 KB: 2 bufs x {Kh,Kl,Vh,Vl}

    const int tid = threadIdx.x, lane = tid & 63, wid = tid >> 6;
    const int l31 = lane & 31, l5 = lane >> 5;
    const int bid = blockIdx.x;
    const int qb = 15 - (bid >> 5), bh = bid & 31;   // heavy q-tiles first
    const int Q0 = qb * 128;
    const int qg = Q0 + wid * 32 + l31;              // this lane's q row

    // Q fragments from global (once per block)
    s16x8 qfh[4], qfl[4];
    {
        const size_t qo = ((size_t)bh * SEQ + qg) * DH;
#pragma unroll
        for (int t = 0; t < 4; ++t) {
            const int ch = t * 2 + l5;
            qfh[t] = *(const s16x8*)&Qh_g[qo + ch * 8];
            qfl[t] = *(const s16x8*)&Ql_g[qo + ch * 8];
        }
    }

    float m_i = -INFINITY, l_i = 0.f;
    f32x16 yacc[2];
#pragma unroll
    for (int e = 0; e < 16; ++e) { yacc[0][e] = 0.f; yacc[1][e] = 0.f; }

    const int srow = lane >> 3, ss = lane & 7;
    const int KT = 2 * qb + 2;
    const unsigned short* gb = (wid == 0) ? Kh_g : (wid == 1) ? Kl_g
                             : (wid == 2) ? Vh_g : Vl_g;
    const bool isK = (wid < 2);

    // prologue: stage kv-tile 0 into buf 0
    {
        short* lb = &SM[0][wid * 4096];
#pragma unroll
        for (int j = 0; j < 8; ++j) {
            int row = j * 8 + srow;
            int kc = ss ^ (row & 7);
            const unsigned short* src = isK
                ? gb + ((size_t)bh * SEQ + row) * DH + kc * 8
                : gb + ((size_t)bh * DH + row) * SEQ + kc * 8;
            gload16(src, lb + j * 512);
        }
    }

    for (int kt = 0; kt < KT; ++kt) {
        const int cur = kt & 1;
        __syncthreads();   // stage(kt) landed; reads of buf[cur] (kt-2) done
        if (kt + 1 < KT) {
            short* lb = &SM[cur ^ 1][wid * 4096];
            const int kn = (kt + 1) * 64;
#pragma unroll
            for (int j = 0; j < 8; ++j) {
                int row = j * 8 + srow;
                int kc = ss ^ (row & 7);
                const unsigned short* src = isK
                    ? gb + ((size_t)bh * SEQ + kn + row) * DH + kc * 8
                    : gb + ((size_t)bh * DH + row) * SEQ + kn + kc * 8;
                gload16(src, lb + j * 512);
            }
        }

        if (kt * 64 > Q0 + wid * 32 + 31) continue;   // fully masked for this wave

        const short* Ksh = &SM[cur][0];
        const short* Ksl = &SM[cur][4096];
        const short* Vsh = &SM[cur][8192];
        const short* Vsl = &SM[cur][12288];

        // ---- S^T = K . Q  (3-combo split; interleaved kb -> distance-2 chains)
        f32x16 s[2];
#pragma unroll
        for (int e = 0; e < 16; ++e) { s[0][e] = 0.f; s[1][e] = 0.f; }
#pragma unroll
        for (int t = 0; t < 4; ++t) {
            s16x8 kh[2], kl[2];
#pragma unroll
            for (int kb = 0; kb < 2; ++kb) {
                const int row = kb * 32 + l31;
                const int sl = ((t * 2 + l5) ^ (row & 7)) * 8;
                kh[kb] = *(const s16x8*)&Ksh[row * 64 + sl];
                kl[kb] = *(const s16x8*)&Ksl[row * 64 + sl];
            }
#pragma unroll
            for (int kb = 0; kb < 2; ++kb) s[kb] = MFMA32(kh[kb], qfh[t], s[kb]);
#pragma unroll
            for (int kb = 0; kb < 2; ++kb) s[kb] = MFMA32(kl[kb], qfh[t], s[kb]);
#pragma unroll
            for (int kb = 0; kb < 2; ++kb) s[kb] = MFMA32(kh[kb], qfl[t], s[kb]);
        }

        // ---- causal mask (only near the diagonal)
        if (kt * 64 + 63 > Q0 + wid * 32) {
#pragma unroll
            for (int kb = 0; kb < 2; ++kb)
#pragma unroll
                for (int r = 0; r < 16; ++r) {
                    const int key = kt * 64 + kb * 32 + (r & 3) + 8 * (r >> 2) + 4 * l5;
                    if (key > qg) s[kb][r] = -INFINITY;
                }
        }

        // ---- online softmax, in-register (q = lane&31), defer-max THR=8
        float mx = s[0][0];
#pragma unroll
        for (int r = 1; r < 16; ++r) mx = fmaxf(mx, s[0][r]);
#pragma unroll
        for (int r = 0; r < 16; ++r) mx = fmaxf(mx, s[1][r]);
        mx = fmaxf(mx, __shfl_xor(mx, 32));
        const bool defer = (__all(mx - m_i <= 8.f) != 0);
        float mref;
        if (defer) {
            mref = m_i;
        } else {
            mref = fmaxf(m_i, mx);
            const float al = __expf(m_i - mref);
            m_i = mref;
            l_i *= al;
#pragma unroll
            for (int e = 0; e < 16; ++e) { yacc[0][e] *= al; yacc[1][e] *= al; }
        }
        float ls = 0.f;
#pragma unroll
        for (int kb = 0; kb < 2; ++kb)
#pragma unroll
            for (int r = 0; r < 16; ++r) {
                s[kb][r] = __expf(s[kb][r] - mref);
                ls += s[kb][r];
            }
        ls += __shfl_xor(ls, 32);
        l_i += ls;

        // ---- P (bf16) fragments in-register: cvt_pk + permlane32_swap
        unsigned pk[2][8];
#pragma unroll
        for (int kb = 0; kb < 2; ++kb)
#pragma unroll
            for (int j = 0; j < 8; ++j)
                pk[kb][j] = cvt_pk_bf16(s[kb][2 * j], s[kb][2 * j + 1]);
        s16x8 pf[2][2];
#pragma unroll
        for (int kb = 0; kb < 2; ++kb) {
            u32x2 sA = __builtin_amdgcn_permlane32_swap(pk[kb][0], pk[kb][2], false, false);
            u32x2 sB = __builtin_amdgcn_permlane32_swap(pk[kb][1], pk[kb][3], false, false);
            u32x4 w0 = {sA[0], sB[0], sA[1], sB[1]};
            pf[kb][0] = __builtin_bit_cast(s16x8, w0);
            u32x2 sC = __builtin_amdgcn_permlane32_swap(pk[kb][4], pk[kb][6], false, false);
            u32x2 sD = __builtin_amdgcn_permlane32_swap(pk[kb][5], pk[kb][7], false, false);
            u32x4 w1 = {sC[0], sD[0], sC[1], sD[1]};
            pf[kb][1] = __builtin_bit_cast(s16x8, w1);
        }

        // ---- Y^T += V^T . P  (interleaved dt -> distance-2 chains)
#pragma unroll
        for (int t = 0; t < 4; ++t) {
            s16x8 vh[2], vl[2];
#pragma unroll
            for (int dt = 0; dt < 2; ++dt) {
                const int row = dt * 32 + l31;
                const int sl = ((t * 2 + l5) ^ (row & 7)) * 8;
                vh[dt] = *(const s16x8*)&Vsh[row * 64 + sl];
                vl[dt] = *(const s16x8*)&Vsl[row * 64 + sl];
            }
            const s16x8 pfr = pf[t >> 1][t & 1];
#pragma unroll
            for (int dt = 0; dt < 2; ++dt) yacc[dt] = MFMA32(vh[dt], pfr, yacc[dt]);
#pragma unroll
            for (int dt = 0; dt < 2; ++dt) yacc[dt] = MFMA32(vl[dt], pfr, yacc[dt]);
        }
    }

    // ---- epilogue: normalize, split, LDS transpose bounce, coalesced write
    __syncthreads();   // everyone done with K/V LDS
    short* SMf = &SM[0][0];
    const float inv = 1.f / l_i;
    const int qlcl = wid * 32 + l31;
#pragma unroll
    for (int dt = 0; dt < 2; ++dt)
#pragma unroll
        for (int rq = 0; rq < 4; ++rq) {
            const int d0 = dt * 32 + rq * 8 + 4 * l5;
            s16x4 h4, l4;
#pragma unroll
            for (int c = 0; c < 4; ++c) {
                unsigned short hh, ll;
                split2(yacc[dt][rq * 4 + c] * inv, hh, ll);
                h4[c] = (short)hh; l4[c] = (short)ll;
            }
            const int base = qlcl * 64 + (((d0 >> 3) ^ (qlcl & 7)) * 8) + (d0 & 7);
            *(s16x4*)&SMf[base] = h4;
            *(s16x4*)&SMf[8192 + base] = l4;
        }
    __syncthreads();
    const int b = bh >> 4, h = bh & 15;
#pragma unroll
    for (int i = 0; i < 4; ++i) {
        const int idx = tid + i * 256;
        const int row = idx >> 3, ch = idx & 7;
        const int sl = (ch ^ (row & 7)) * 8;
        s16x8 vh8 = *(const s16x8*)&SMf[row * 64 + sl];
        s16x8 vl8 = *(const s16x8*)&SMf[8192 + row * 64 + sl];
        const size_t o = ((size_t)(b * SEQ + Q0 + row)) * EMBED + h * DH + ch * 8;
        *(s16x8*)&Yh[o] = vh8;
        *(s16x8*)&Yl[o] = vl8;
    }
}

// ---------------------------------------------------------------------------
// Out GEMM: 2-phase pipelined staging, XCD-swizzled, combo-outer MFMA.
// (Grid-limited to 1 block/CU, so 64 KB dbuf costs no occupancy.) (unchanged)
// ---------------------------------------------------------------------------
__global__ __launch_bounds__(256)
void out_gemm_kernel(const unsigned short* __restrict__ Yh_g, const unsigned short* __restrict__ Yl_g,
                     const unsigned short* __restrict__ WhT, const unsigned short* __restrict__ WlT,
                     const float* __restrict__ bias, float* __restrict__ out)
{
    constexpr int KD = 1024, ND = 1024;
    __shared__ __align__(16) short SB[2][16384];   // 64 KB

    const int tid = threadIdx.x, lane = tid & 63, wid = tid >> 6;
    const int g = lane >> 4, ln = lane & 15;
    const int wm = wid >> 1, wn = wid & 1;

    const int bid = blockIdx.x;
    const int u = bid >> 3, xcd = bid & 7;
    const int by = xcd * 4 + (u & 3);   // m-tile 0..31
    const int bx = u >> 2;              // n-tile 0..7
    const int m0 = by * 128, n0 = bx * 128;

    f32x4 acc[4][4];
#pragma unroll
    for (int i = 0; i < 4; ++i)
#pragma unroll
        for (int j = 0; j < 4; ++j) acc[i][j] = (f32x4){0.f, 0.f, 0.f, 0.f};

    const int srow = lane >> 2, ss = lane & 3;
    const unsigned short* gb = (wid == 0) ? Yh_g : (wid == 1) ? Yl_g
                             : (wid == 2) ? WhT  : WlT;
    const int roff = (wid < 2) ? m0 : n0;

    {
        short* lb = &SB[0][wid * 4096];
#pragma unroll
        for (int j = 0; j < 8; ++j) {
            int row_loc = j * 16 + srow;
            int kc = ss ^ ((row_loc >> 1) & 3);
            gload16(gb + (size_t)(roff + row_loc) * KD + kc * 8, lb + j * 512);
        }
    }

    for (int it = 0; it < 32; ++it) {
        const int cur = it & 1;
        __syncthreads();
        if (it + 1 < 32) {
            short* lb = &SB[cur ^ 1][wid * 4096];
            const int k0n = (it + 1) * 32;
#pragma unroll
            for (int j = 0; j < 8; ++j) {
                int row_loc = j * 16 + srow;
                int kc = ss ^ ((row_loc >> 1) & 3);
                gload16(gb + (size_t)(roff + row_loc) * KD + k0n + kc * 8, lb + j * 512);
            }
        }
        const short* Ah = &SB[cur][0];
        const short* Al = &SB[cur][4096];
        const short* Bh = &SB[cur][8192];
        const short* Bl = &SB[cur][12288];

        s16x8 fah[4], fal[4], fbh[4], fbl[4];
#pragma unroll
        for (int am = 0; am < 4; ++am) {
            int m_loc = wm * 64 + am * 16 + ln;
            int sl = (g ^ ((m_loc >> 1) & 3)) * 8;
            fah[am] = *(const s16x8*)&Ah[m_loc * 32 + sl];
            fal[am] = *(const s16x8*)&Al[m_loc * 32 + sl];
        }
#pragma unroll
        for (int bn = 0; bn < 4; ++bn) {
            int n_loc = wn * 64 + bn * 16 + ln;
            int sl = (g ^ ((n_loc >> 1) & 3)) * 8;
            fbh[bn] = *(const s16x8*)&Bh[n_loc * 32 + sl];
            fbl[bn] = *(const s16x8*)&Bl[n_loc * 32 + sl];
        }
#pragma unroll
        for (int am = 0; am < 4; ++am)
#pragma unroll
            for (int bn = 0; bn < 4; ++bn)
                acc[am][bn] = MFMA16(fah[am], fbh[bn], acc[am][bn]);
#pragma unroll
        for (int am = 0; am < 4; ++am)
#pragma unroll
            for (int bn = 0; bn < 4; ++bn)
                acc[am][bn] = MFMA16(fah[am], fbl[bn], acc[am][bn]);
#pragma unroll
        for (int am = 0; am < 4; ++am)
#pragma unroll
            for (int bn = 0; bn < 4; ++bn)
                acc[am][bn] = MFMA16(fal[am], fbh[bn], acc[am][bn]);
    }

#pragma unroll
    for (int am = 0; am < 4; ++am)
#pragma unroll
        for (int bn = 0; bn < 4; ++bn) {
            int n = n0 + wn * 64 + bn * 16 + ln;
            float bv = bias[n];
#pragma unroll
            for (int r = 0; r < 4; ++r) {
                int m = m0 + wm * 64 + am * 16 + g * 4 + r;
                out[(size_t)m * ND + n] = acc[am][bn][r] + bv;
            }
        }
}

// ---------------------------------------------------------------------------
extern "C" void kernel_launch(void* const* d_in, const int* in_sizes, int n_in,
                              void* d_out, int out_size, void* d_ws, size_t ws_size,
                              hipStream_t stream)
{
    const float* x     = (const float*)d_in[0];
    const float* W_kqv = (const float*)d_in[1];
    const float* b_kqv = (const float*)d_in[2];
    const float* W_out = (const float*)d_in[3];
    const float* b_out = (const float*)d_in[4];
    float* out = (float*)d_out;

    char* ws = (char*)d_ws;
    const size_t MB = 1024 * 1024;
    unsigned short* Qh = (unsigned short*)(ws);
    unsigned short* Ql = Qh + 4194304;
    unsigned short* Kh = Ql + 4194304;
    unsigned short* Kl = Kh + 4194304;
    unsigned short* Vh = Kl + 4194304;
    unsigned short* Vl = Vh + 4194304;
    unsigned short* WhT = (unsigned short*)(ws + 48 * MB);
    unsigned short* WlT = WhT + 3145728;
    unsigned short* Yh  = (unsigned short*)(ws + 48 * MB);
    unsigned short* Yl  = Yh + 4194304;
    unsigned short* WoTh = (unsigned short*)(ws);
    unsigned short* WoTl = WoTh + 1048576;
    // X split lives in d_out (16 MB): dead until out_gemm rewrites all of it.
    unsigned short* Xh = (unsigned short*)d_out;
    unsigned short* Xl = Xh + 4194304;

    splitX_kernel<<<dim3(MTOT * EMBED / (256 * 8)), 256, 0, stream>>>(x, Xh, Xl);
    splitT_kernel<<<dim3(3 * EMBED / 32, EMBED / 32), 256, 0, stream>>>(
        W_kqv, WhT, WlT, EMBED, 3 * EMBED);
    qkv_gemm_kernel<<<dim3(1536), 256, 0, stream>>>(
        Xh, Xl, WhT, WlT, b_kqv, Qh, Ql, Kh, Kl, Vh, Vl);
    attn_kernel<<<dim3(BHTOT * (SEQ / 128)), 256, 0, stream>>>(
        Qh, Ql, Kh, Kl, Vh, Vl, Yh, Yl);
    splitT_kernel<<<dim3(EMBED / 32, EMBED / 32), 256, 0, stream>>>(
        W_out, WoTh, WoTl, EMBED, EMBED);
    out_gemm_kernel<<<dim3(256), 256, 0, stream>>>(
        Yh, Yl, WoTh, WoTl, b_out, out);
}

// Round 11
// 192.646 us; speedup vs baseline: 1.1210x; 1.1210x over previous
//
#include <hip/hip_runtime.h>
#include <math.h>

#define EMBED 1024
#define NH    16
#define DH    64
#define BATCH 2
#define SEQ   2048
#define MTOT  4096
#define BHTOT 32

typedef float f32x4  __attribute__((ext_vector_type(4)));
typedef float f32x16 __attribute__((ext_vector_type(16)));
typedef short s16x8  __attribute__((ext_vector_type(8)));
typedef short s16x4  __attribute__((ext_vector_type(4)));
typedef unsigned u32x2 __attribute__((ext_vector_type(2)));
typedef unsigned u32x4 __attribute__((ext_vector_type(4)));

#define AS1 __attribute__((address_space(1)))
#define AS3 __attribute__((address_space(3)))

__device__ __forceinline__ unsigned short bf16_rne(float f) {
    unsigned u = __builtin_bit_cast(unsigned, f);
    return (unsigned short)((u + 0x7FFFu + ((u >> 16) & 1u)) >> 16);
}
__device__ __forceinline__ float bf16_f(unsigned short h) {
    unsigned u = ((unsigned)h) << 16;
    return __builtin_bit_cast(float, u);
}
__device__ __forceinline__ void split2(float v, unsigned short& hi, unsigned short& lo) {
    hi = bf16_rne(v);
    lo = bf16_rne(v - bf16_f(hi));
}
__device__ __forceinline__ void gload16(const void* g, void* l) {
    __builtin_amdgcn_global_load_lds((const AS1 void*)g, (AS3 void*)l, 16, 0, 0);
}
__device__ __forceinline__ unsigned cvt_pk_bf16(float lo, float hi) {
    unsigned r;
    asm volatile("v_cvt_pk_bf16_f32 %0, %1, %2" : "=v"(r) : "v"(lo), "v"(hi));
    return r;
}
#define MFMA16(a, b, c) __builtin_amdgcn_mfma_f32_16x16x32_bf16((a), (b), (c), 0, 0, 0)
#define MFMA32(a, b, c) __builtin_amdgcn_mfma_f32_32x32x16_bf16((a), (b), (c), 0, 0, 0)

// ---------------------------------------------------------------------------
// splitX: X fp32 [M][K] -> Xh bf16 only (lo word no longer needed by qkv)
// ---------------------------------------------------------------------------
__global__ __launch_bounds__(256)
void splitX_kernel(const float* __restrict__ X, unsigned short* __restrict__ Xh)
{
    const size_t i = ((size_t)blockIdx.x * 256 + threadIdx.x) * 8;
    float4 a = *(const float4*)&X[i];
    float4 b = *(const float4*)&X[i + 4];
    float v[8] = {a.x, a.y, a.z, a.w, b.x, b.y, b.z, b.w};
    s16x8 h8;
#pragma unroll
    for (int e = 0; e < 8; ++e) h8[e] = (short)bf16_rne(v[e]);
    *(s16x8*)&Xh[i] = h8;
}

// ---------------------------------------------------------------------------
// splitT: W fp32 [Kd][Nd]  ->  HiT, LoT bf16 [Nd][Kd] (transposed + hi/lo split)
// ---------------------------------------------------------------------------
__global__ __launch_bounds__(256)
void splitT_kernel(const float* __restrict__ W, unsigned short* __restrict__ HiT,
                   unsigned short* __restrict__ LoT, int Kd, int Nd)
{
    __shared__ float T[32][33];
    const int tid = threadIdx.x;
    const int n0 = blockIdx.x * 32, k0 = blockIdx.y * 32;
    {
        const int row = tid >> 3, c4 = (tid & 7) * 4;
        float4 v = *(const float4*)&W[(size_t)(k0 + row) * Nd + n0 + c4];
        T[row][c4] = v.x; T[row][c4 + 1] = v.y; T[row][c4 + 2] = v.z; T[row][c4 + 3] = v.w;
    }
    __syncthreads();
    {
        const int nr = tid >> 3, c4 = (tid & 7) * 4;
        s16x4 h4, l4;
#pragma unroll
        for (int e = 0; e < 4; ++e) {
            unsigned short h, l;
            split2(T[c4 + e][nr], h, l);
            h4[e] = (short)h; l4[e] = (short)l;
        }
        *(s16x4*)&HiT[(size_t)(n0 + nr) * Kd + k0 + c4] = h4;
        *(s16x4*)&LoT[(size_t)(n0 + nr) * Kd + k0 + c4] = l4;
    }
}

// ---------------------------------------------------------------------------
// QKV GEMM, 2-combo split (Ah.Bh + Ah.Bl; X in plain bf16, W in hi+lo):
// 128x128 tile, BK=32, 3 tiles (24 KB) -> DOUBLE-BUFFERED in 48 KB at
// 3 blocks/CU. Issue-early staging, XCD-swizzled grid, combo-outer MFMA.
// ---------------------------------------------------------------------------
__global__ __launch_bounds__(256)
void qkv_gemm_kernel(const unsigned short* __restrict__ Xh_g,
                     const unsigned short* __restrict__ BhT, const unsigned short* __restrict__ BlT,
                     const float* __restrict__ bias,
                     unsigned short* __restrict__ Qh, unsigned short* __restrict__ Ql,
                     unsigned short* __restrict__ Kh, unsigned short* __restrict__ Kl,
                     unsigned short* __restrict__ Vh, unsigned short* __restrict__ Vl)
{
    constexpr int KD = 1024;
    // per buf (shorts): Ah [0,4096) Bh [4096,8192) Bl [8192,12288)
    __shared__ __align__(16) short SB[2][12288];   // 48 KB total

    const int tid = threadIdx.x, lane = tid & 63, wid = tid >> 6;
    const int g = lane >> 4, ln = lane & 15;
    const int wm = wid >> 1, wn = wid & 1;

    // XCD swizzle: xcd = bid&7 owns 96 tiles = 4 m-rows x 24 n (m-fastest)
    const int bid = blockIdx.x;
    const int u = bid >> 3, xcd = bid & 7;
    const int by = xcd * 4 + (u & 3);   // m-tile 0..31
    const int bx = u >> 2;              // n-tile 0..23
    const int m0 = by * 128, n0 = bx * 128;

    f32x4 acc[4][4];
#pragma unroll
    for (int i = 0; i < 4; ++i)
#pragma unroll
        for (int j = 0; j < 4; ++j) acc[i][j] = (f32x4){0.f, 0.f, 0.f, 0.f};

    const int srow = lane >> 2, ss = lane & 3;

    // 24 staging segments (3 tiles x 8), 6 per wave.
    // segment s: tile t=s>>3 (0=Ah,1=Bh,2=Bl), sub j=s&7.
    // prologue: stage k-tile 0 into buf 0
    {
#pragma unroll
        for (int i = 0; i < 6; ++i) {
            const int s = wid * 6 + i;
            const int t = s >> 3, j = s & 7;
            const unsigned short* gsrc = (t == 0) ? Xh_g : (t == 1) ? BhT : BlT;
            const int roff = (t == 0) ? m0 : n0;
            const int row_loc = j * 16 + srow;
            const int kc = ss ^ ((row_loc >> 1) & 3);
            gload16(gsrc + (size_t)(roff + row_loc) * KD + kc * 8,
                    &SB[0][t * 4096 + j * 512]);
        }
    }

    for (int it = 0; it < 32; ++it) {
        const int cur = it & 1;
        __syncthreads();   // stage(it) landed; reads of buf[cur] (iter it-2) done
        if (it + 1 < 32) {
            const int k0n = (it + 1) * 32;
#pragma unroll
            for (int i = 0; i < 6; ++i) {
                const int s = wid * 6 + i;
                const int t = s >> 3, j = s & 7;
                const unsigned short* gsrc = (t == 0) ? Xh_g : (t == 1) ? BhT : BlT;
                const int roff = (t == 0) ? m0 : n0;
                const int row_loc = j * 16 + srow;
                const int kc = ss ^ ((row_loc >> 1) & 3);
                gload16(gsrc + (size_t)(roff + row_loc) * KD + k0n + kc * 8,
                        &SB[cur ^ 1][t * 4096 + j * 512]);
            }
        }
        const short* Ah = &SB[cur][0];
        const short* Bh = &SB[cur][4096];
        const short* Bl = &SB[cur][8192];

        s16x8 fah[4], fbh[4], fbl[4];
#pragma unroll
        for (int am = 0; am < 4; ++am) {
            int m_loc = wm * 64 + am * 16 + ln;
            int sl = (g ^ ((m_loc >> 1) & 3)) * 8;
            fah[am] = *(const s16x8*)&Ah[m_loc * 32 + sl];
        }
#pragma unroll
        for (int bn = 0; bn < 4; ++bn) {
            int n_loc = wn * 64 + bn * 16 + ln;
            int sl = (g ^ ((n_loc >> 1) & 3)) * 8;
            fbh[bn] = *(const s16x8*)&Bh[n_loc * 32 + sl];
            fbl[bn] = *(const s16x8*)&Bl[n_loc * 32 + sl];
        }
        // combo-outer: reuse distance 16 on each accumulator
#pragma unroll
        for (int am = 0; am < 4; ++am)
#pragma unroll
            for (int bn = 0; bn < 4; ++bn)
                acc[am][bn] = MFMA16(fah[am], fbh[bn], acc[am][bn]);
#pragma unroll
        for (int am = 0; am < 4; ++am)
#pragma unroll
            for (int bn = 0; bn < 4; ++bn)
                acc[am][bn] = MFMA16(fah[am], fbl[bn], acc[am][bn]);
    }

    // epilogue: bias + split scatter (C/D: row=(lane>>4)*4+r, col=lane&15)
#pragma unroll
    for (int am = 0; am < 4; ++am)
#pragma unroll
        for (int bn = 0; bn < 4; ++bn) {
            int n = n0 + wn * 64 + bn * 16 + ln;
            float bv = bias[n];
            int sec = n >> 10, cc = n & 1023, h = cc >> 6, d = cc & 63;
#pragma unroll
            for (int r = 0; r < 4; ++r) {
                int m = m0 + wm * 64 + am * 16 + g * 4 + r;
                int bb = m >> 11, t = m & 2047;
                int bh_i = bb * NH + h;
                float val = acc[am][bn][r] + bv;
                unsigned short hi, lo;
                if (sec == 0) {
                    val *= 0.125f; split2(val, hi, lo);
                    size_t idx = ((size_t)bh_i * SEQ + t) * DH + d;
                    Qh[idx] = hi; Ql[idx] = lo;
                } else if (sec == 1) {
                    split2(val, hi, lo);
                    size_t idx = ((size_t)bh_i * SEQ + t) * DH + d;
                    Kh[idx] = hi; Kl[idx] = lo;
                } else {
                    split2(val, hi, lo);
                    size_t idx = ((size_t)bh_i * DH + d) * SEQ + t;   // V transposed
                    Vh[idx] = hi; Vl[idx] = lo;
                }
            }
        }
}

// ---------------------------------------------------------------------------
// Attention, 32x32 swapped-operand structure + 2-phase pipelined K/V staging
// (double-buffered, 64 KB LDS). Defer-max THR=8; interleaved MFMA
// accumulators. (unchanged from r9)
// ---------------------------------------------------------------------------
__global__ __launch_bounds__(256)
void attn_kernel(const unsigned short* __restrict__ Qh_g, const unsigned short* __restrict__ Ql_g,
                 const unsigned short* __restrict__ Kh_g, const unsigned short* __restrict__ Kl_g,
                 const unsigned short* __restrict__ Vh_g, const unsigned short* __restrict__ Vl_g,
                 unsigned short* __restrict__ Yh, unsigned short* __restrict__ Yl)
{
    __shared__ __align__(16) short SM[2][16384];   // 64 KB: 2 bufs x {Kh,Kl,Vh,Vl}

    const int tid = threadIdx.x, lane = tid & 63, wid = tid >> 6;
    const int l31 = lane & 31, l5 = lane >> 5;
    const int bid = blockIdx.x;
    const int qb = 15 - (bid >> 5), bh = bid & 31;   // heavy q-tiles first
    const int Q0 = qb * 128;
    const int qg = Q0 + wid * 32 + l31;              // this lane's q row

    // Q fragments from global (once per block)
    s16x8 qfh[4], qfl[4];
    {
        const size_t qo = ((size_t)bh * SEQ + qg) * DH;
#pragma unroll
        for (int t = 0; t < 4; ++t) {
            const int ch = t * 2 + l5;
            qfh[t] = *(const s16x8*)&Qh_g[qo + ch * 8];
            qfl[t] = *(const s16x8*)&Ql_g[qo + ch * 8];
        }
    }

    float m_i = -INFINITY, l_i = 0.f;
    f32x16 yacc[2];
#pragma unroll
    for (int e = 0; e < 16; ++e) { yacc[0][e] = 0.f; yacc[1][e] = 0.f; }

    const int srow = lane >> 3, ss = lane & 7;
    const int KT = 2 * qb + 2;
    const unsigned short* gb = (wid == 0) ? Kh_g : (wid == 1) ? Kl_g
                             : (wid == 2) ? Vh_g : Vl_g;
    const bool isK = (wid < 2);

    // prologue: stage kv-tile 0 into buf 0
    {
        short* lb = &SM[0][wid * 4096];
#pragma unroll
        for (int j = 0; j < 8; ++j) {
            int row = j * 8 + srow;
            int kc = ss ^ (row & 7);
            const unsigned short* src = isK
                ? gb + ((size_t)bh * SEQ + row) * DH + kc * 8
                : gb + ((size_t)bh * DH + row) * SEQ + kc * 8;
            gload16(src, lb + j * 512);
        }
    }

    for (int kt = 0; kt < KT; ++kt) {
        const int cur = kt & 1;
        __syncthreads();   // stage(kt) landed; reads of buf[cur] (kt-2) done
        if (kt + 1 < KT) {
            short* lb = &SM[cur ^ 1][wid * 4096];
            const int kn = (kt + 1) * 64;
#pragma unroll
            for (int j = 0; j < 8; ++j) {
                int row = j * 8 + srow;
                int kc = ss ^ (row & 7);
                const unsigned short* src = isK
                    ? gb + ((size_t)bh * SEQ + kn + row) * DH + kc * 8
                    : gb + ((size_t)bh * DH + row) * SEQ + kn + kc * 8;
                gload16(src, lb + j * 512);
            }
        }

        if (kt * 64 > Q0 + wid * 32 + 31) continue;   // fully masked for this wave

        const short* Ksh = &SM[cur][0];
        const short* Ksl = &SM[cur][4096];
        const short* Vsh = &SM[cur][8192];
        const short* Vsl = &SM[cur][12288];

        // ---- S^T = K . Q  (3-combo split; interleaved kb -> distance-2 chains)
        f32x16 s[2];
#pragma unroll
        for (int e = 0; e < 16; ++e) { s[0][e] = 0.f; s[1][e] = 0.f; }
#pragma unroll
        for (int t = 0; t < 4; ++t) {
            s16x8 kh[2], kl[2];
#pragma unroll
            for (int kb = 0; kb < 2; ++kb) {
                const int row = kb * 32 + l31;
                const int sl = ((t * 2 + l5) ^ (row & 7)) * 8;
                kh[kb] = *(const s16x8*)&Ksh[row * 64 + sl];
                kl[kb] = *(const s16x8*)&Ksl[row * 64 + sl];
            }
#pragma unroll
            for (int kb = 0; kb < 2; ++kb) s[kb] = MFMA32(kh[kb], qfh[t], s[kb]);
#pragma unroll
            for (int kb = 0; kb < 2; ++kb) s[kb] = MFMA32(kl[kb], qfh[t], s[kb]);
#pragma unroll
            for (int kb = 0; kb < 2; ++kb) s[kb] = MFMA32(kh[kb], qfl[t], s[kb]);
        }

        // ---- causal mask (only near the diagonal)
        if (kt * 64 + 63 > Q0 + wid * 32) {
#pragma unroll
            for (int kb = 0; kb < 2; ++kb)
#pragma unroll
                for (int r = 0; r < 16; ++r) {
                    const int key = kt * 64 + kb * 32 + (r & 3) + 8 * (r >> 2) + 4 * l5;
                    if (key > qg) s[kb][r] = -INFINITY;
                }
        }

        // ---- online softmax, in-register (q = lane&31), defer-max THR=8
        float mx = s[0][0];
#pragma unroll
        for (int r = 1; r < 16; ++r) mx = fmaxf(mx, s[0][r]);
#pragma unroll
        for (int r = 0; r < 16; ++r) mx = fmaxf(mx, s[1][r]);
        mx = fmaxf(mx, __shfl_xor(mx, 32));
        const bool defer = (__all(mx - m_i <= 8.f) != 0);
        float mref;
        if (defer) {
            mref = m_i;
        } else {
            mref = fmaxf(m_i, mx);
            const float al = __expf(m_i - mref);
            m_i = mref;
            l_i *= al;
#pragma unroll
            for (int e = 0; e < 16; ++e) { yacc[0][e] *= al; yacc[1][e] *= al; }
        }
        float ls = 0.f;
#pragma unroll
        for (int kb = 0; kb < 2; ++kb)
#pragma unroll
            for (int r = 0; r < 16; ++r) {
                s[kb][r] = __expf(s[kb][r] - mref);
                ls += s[kb][r];
            }
        ls += __shfl_xor(ls, 32);
        l_i += ls;

        // ---- P (bf16) fragments in-register: cvt_pk + permlane32_swap
        unsigned pk[2][8];
#pragma unroll
        for (int kb = 0; kb < 2; ++kb)
#pragma unroll
            for (int j = 0; j < 8; ++j)
                pk[kb][j] = cvt_pk_bf16(s[kb][2 * j], s[kb][2 * j + 1]);
        s16x8 pf[2][2];
#pragma unroll
        for (int kb = 0; kb < 2; ++kb) {
            u32x2 sA = __builtin_amdgcn_permlane32_swap(pk[kb][0], pk[kb][2], false, false);
            u32x2 sB = __builtin_amdgcn_permlane32_swap(pk[kb][1], pk[kb][3], false, false);
            u32x4 w0 = {sA[0], sB[0], sA[1], sB[1]};
            pf[kb][0] = __builtin_bit_cast(s16x8, w0);
            u32x2 sC = __builtin_amdgcn_permlane32_swap(pk[kb][4], pk[kb][6], false, false);
            u32x2 sD = __builtin_amdgcn_permlane32_swap(pk[kb][5], pk[kb][7], false, false);
            u32x4 w1 = {sC[0], sD[0], sC[1], sD[1]};
            pf[kb][1] = __builtin_bit_cast(s16x8, w1);
        }

        // ---- Y^T += V^T . P  (interleaved dt -> distance-2 chains)
#pragma unroll
        for (int t = 0; t < 4; ++t) {
            s16x8 vh[2], vl[2];
#pragma unroll
            for (int dt = 0; dt < 2; ++dt) {
                const int row = dt * 32 + l31;
                const int sl = ((t * 2 + l5) ^ (row & 7)) * 8;
                vh[dt] = *(const s16x8*)&Vsh[row * 64 + sl];
                vl[dt] = *(const s16x8*)&Vsl[row * 64 + sl];
            }
            const s16x8 pfr = pf[t >> 1][t & 1];
#pragma unroll
            for (int dt = 0; dt < 2; ++dt) yacc[dt] = MFMA32(vh[dt], pfr, yacc[dt]);
#pragma unroll
            for (int dt = 0; dt < 2; ++dt) yacc[dt] = MFMA32(vl[dt], pfr, yacc[dt]);
        }
    }

    // ---- epilogue: normalize, split, LDS transpose bounce, coalesced write
    __syncthreads();   // everyone done with K/V LDS
    short* SMf = &SM[0][0];
    const float inv = 1.f / l_i;
    const int qlcl = wid * 32 + l31;
#pragma unroll
    for (int dt = 0; dt < 2; ++dt)
#pragma unroll
        for (int rq = 0; rq < 4; ++rq) {
            const int d0 = dt * 32 + rq * 8 + 4 * l5;
            s16x4 h4, l4;
#pragma unroll
            for (int c = 0; c < 4; ++c) {
                unsigned short hh, ll;
                split2(yacc[dt][rq * 4 + c] * inv, hh, ll);
                h4[c] = (short)hh; l4[c] = (short)ll;
            }
            const int base = qlcl * 64 + (((d0 >> 3) ^ (qlcl & 7)) * 8) + (d0 & 7);
            *(s16x4*)&SMf[base] = h4;
            *(s16x4*)&SMf[8192 + base] = l4;
        }
    __syncthreads();
    const int b = bh >> 4, h = bh & 15;
#pragma unroll
    for (int i = 0; i < 4; ++i) {
        const int idx = tid + i * 256;
        const int row = idx >> 3, ch = idx & 7;
        const int sl = (ch ^ (row & 7)) * 8;
        s16x8 vh8 = *(const s16x8*)&SMf[row * 64 + sl];
        s16x8 vl8 = *(const s16x8*)&SMf[8192 + row * 64 + sl];
        const size_t o = ((size_t)(b * SEQ + Q0 + row)) * EMBED + h * DH + ch * 8;
        *(s16x8*)&Yh[o] = vh8;
        *(s16x8*)&Yl[o] = vl8;
    }
}

// ---------------------------------------------------------------------------
// Out GEMM: 2-phase pipelined staging, XCD-swizzled, combo-outer MFMA.
// (Grid-limited to 1 block/CU, so 64 KB dbuf costs no occupancy.) (unchanged)
// ---------------------------------------------------------------------------
__global__ __launch_bounds__(256)
void out_gemm_kernel(const unsigned short* __restrict__ Yh_g, const unsigned short* __restrict__ Yl_g,
                     const unsigned short* __restrict__ WhT, const unsigned short* __restrict__ WlT,
                     const float* __restrict__ bias, float* __restrict__ out)
{
    constexpr int KD = 1024, ND = 1024;
    __shared__ __align__(16) short SB[2][16384];   // 64 KB

    const int tid = threadIdx.x, lane = tid & 63, wid = tid >> 6;
    const int g = lane >> 4, ln = lane & 15;
    const int wm = wid >> 1, wn = wid & 1;

    const int bid = blockIdx.x;
    const int u = bid >> 3, xcd = bid & 7;
    const int by = xcd * 4 + (u & 3);   // m-tile 0..31
    const int bx = u >> 2;              // n-tile 0..7
    const int m0 = by * 128, n0 = bx * 128;

    f32x4 acc[4][4];
#pragma unroll
    for (int i = 0; i < 4; ++i)
#pragma unroll
        for (int j = 0; j < 4; ++j) acc[i][j] = (f32x4){0.f, 0.f, 0.f, 0.f};

    const int srow = lane >> 2, ss = lane & 3;
    const unsigned short* gb = (wid == 0) ? Yh_g : (wid == 1) ? Yl_g
                             : (wid == 2) ? WhT  : WlT;
    const int roff = (wid < 2) ? m0 : n0;

    {
        short* lb = &SB[0][wid * 4096];
#pragma unroll
        for (int j = 0; j < 8; ++j) {
            int row_loc = j * 16 + srow;
            int kc = ss ^ ((row_loc >> 1) & 3);
            gload16(gb + (size_t)(roff + row_loc) * KD + kc * 8, lb + j * 512);
        }
    }

    for (int it = 0; it < 32; ++it) {
        const int cur = it & 1;
        __syncthreads();
        if (it + 1 < 32) {
            short* lb = &SB[cur ^ 1][wid * 4096];
            const int k0n = (it + 1) * 32;
#pragma unroll
            for (int j = 0; j < 8; ++j) {
                int row_loc = j * 16 + srow;
                int kc = ss ^ ((row_loc >> 1) & 3);
                gload16(gb + (size_t)(roff + row_loc) * KD + k0n + kc * 8, lb + j * 512);
            }
        }
        const short* Ah = &SB[cur][0];
        const short* Al = &SB[cur][4096];
        const short* Bh = &SB[cur][8192];
        const short* Bl = &SB[cur][12288];

        s16x8 fah[4], fal[4], fbh[4], fbl[4];
#pragma unroll
        for (int am = 0; am < 4; ++am) {
            int m_loc = wm * 64 + am * 16 + ln;
            int sl = (g ^ ((m_loc >> 1) & 3)) * 8;
            fah[am] = *(const s16x8*)&Ah[m_loc * 32 + sl];
            fal[am] = *(const s16x8*)&Al[m_loc * 32 + sl];
        }
#pragma unroll
        for (int bn = 0; bn < 4; ++bn) {
            int n_loc = wn * 64 + bn * 16 + ln;
            int sl = (g ^ ((n_loc >> 1) & 3)) * 8;
            fbh[bn] = *(const s16x8*)&Bh[n_loc * 32 + sl];
            fbl[bn] = *(const s16x8*)&Bl[n_loc * 32 + sl];
        }
#pragma unroll
        for (int am = 0; am < 4; ++am)
#pragma unroll
            for (int bn = 0; bn < 4; ++bn)
                acc[am][bn] = MFMA16(fah[am], fbh[bn], acc[am][bn]);
#pragma unroll
        for (int am = 0; am < 4; ++am)
#pragma unroll
            for (int bn = 0; bn < 4; ++bn)
                acc[am][bn] = MFMA16(fah[am], fbl[bn], acc[am][bn]);
#pragma unroll
        for (int am = 0; am < 4; ++am)
#pragma unroll
            for (int bn = 0; bn < 4; ++bn)
                acc[am][bn] = MFMA16(fal[am], fbh[bn], acc[am][bn]);
    }

#pragma unroll
    for (int am = 0; am < 4; ++am)
#pragma unroll
        for (int bn = 0; bn < 4; ++bn) {
            int n = n0 + wn * 64 + bn * 16 + ln;
            float bv = bias[n];
#pragma unroll
            for (int r = 0; r < 4; ++r) {
                int m = m0 + wm * 64 + am * 16 + g * 4 + r;
                out[(size_t)m * ND + n] = acc[am][bn][r] + bv;
            }
        }
}

// ---------------------------------------------------------------------------
extern "C" void kernel_launch(void* const* d_in, const int* in_sizes, int n_in,
                              void* d_out, int out_size, void* d_ws, size_t ws_size,
                              hipStream_t stream)
{
    const float* x     = (const float*)d_in[0];
    const float* W_kqv = (const float*)d_in[1];
    const float* b_kqv = (const float*)d_in[2];
    const float* W_out = (const float*)d_in[3];
    const float* b_out = (const float*)d_in[4];
    float* out = (float*)d_out;

    char* ws = (char*)d_ws;
    const size_t MB = 1024 * 1024;
    unsigned short* Qh = (unsigned short*)(ws);
    unsigned short* Ql = Qh + 4194304;
    unsigned short* Kh = Ql + 4194304;
    unsigned short* Kl = Kh + 4194304;
    unsigned short* Vh = Kl + 4194304;
    unsigned short* Vl = Vh + 4194304;
    unsigned short* WhT = (unsigned short*)(ws + 48 * MB);
    unsigned short* WlT = WhT + 3145728;
    unsigned short* Yh  = (unsigned short*)(ws + 48 * MB);
    unsigned short* Yl  = Yh + 4194304;
    unsigned short* WoTh = (unsigned short*)(ws);
    unsigned short* WoTl = WoTh + 1048576;
    // Xh lives in d_out (8 MB of 16): dead until out_gemm rewrites all of it.
    unsigned short* Xh = (unsigned short*)d_out;

    splitX_kernel<<<dim3(MTOT * EMBED / (256 * 8)), 256, 0, stream>>>(x, Xh);
    splitT_kernel<<<dim3(3 * EMBED / 32, EMBED / 32), 256, 0, stream>>>(
        W_kqv, WhT, WlT, EMBED, 3 * EMBED);
    qkv_gemm_kernel<<<dim3(768), 256, 0, stream>>>(
        Xh, WhT, WlT, b_kqv, Qh, Ql, Kh, Kl, Vh, Vl);
    attn_kernel<<<dim3(BHTOT * (SEQ / 128)), 256, 0, stream>>>(
        Qh, Ql, Kh, Kl, Vh, Vl, Yh, Yl);
    splitT_kernel<<<dim3(EMBED / 32, EMBED / 32), 256, 0, stream>>>(
        W_out, WoTh, WoTl, EMBED, EMBED);
    out_gemm_kernel<<<dim3(256), 256, 0, stream>>>(
        Yh, Yl, WoTh, WoTl, b_out, out);
}